// Round 3
// baseline (375.155 us; speedup 1.0000x reference)
//
#include <hip/hip_runtime.h>
#include <hip/hip_bf16.h>
#include <math.h>

#define B_TOT 262144

typedef __attribute__((ext_vector_type(8))) short v8s;
typedef __attribute__((ext_vector_type(4))) float v4f;

// ws layout (bf16 element offsets):
//  W1 frag-order   [0, 20480)        (8 n-tiles x 5 k-chunks x 512)
//  W2 frag-order   [20480, 36864)    (8 x 4 x 512)
//  Wf frag-order   [36864, 53248)    (8 x 4 x 512)
//  seen frag-order [53248, 67584)    (7 x 4 x 512, rows >=100 zero-padded)
//  s2 (fp32)       byte offset 135168, 112 floats (1e30 for pad rows)
#define WS_W1 0
#define WS_W2 20480
#define WS_WF 36864
#define WS_SEEN 53248
#define WS_S2_BYTES 135168

#define MFMA __builtin_amdgcn_mfma_f32_16x16x32_bf16

__device__ __forceinline__ unsigned short f2bf(float f) {
  union { float f; unsigned u; } cv; cv.f = f;
  unsigned u = cv.u;
  return (unsigned short)((u + 0x7FFFu + ((u >> 16) & 1u)) >> 16);  // RNE
}
__device__ __forceinline__ float bf2f(unsigned short h) {
  union { unsigned u; float f; } cv; cv.u = ((unsigned)h) << 16;
  return cv.f;
}
// packed RNE f32x2 -> bf16x2 (v_cvt_pk_bf16_f32 on gfx950); low 16 = x
__device__ __forceinline__ unsigned f2bf2(float x, float y) {
  float2 f; f.x = x; f.y = y;
  __hip_bfloat162 h = __float22bfloat162_rn(f);
  union { __hip_bfloat162 h; unsigned u; } cv; cv.h = h;
  return cv.u;
}

// Repack weights to bf16 in MFMA B-fragment-linear order.
// B-frag for (tile t, k-chunk c): lane L holds B[n = t*16 + (L&15)][k = c*32 + (L>>4)*8 + j]
__global__ void curiosity_prep(const float* __restrict__ W1, const float* __restrict__ W2,
                               const float* __restrict__ Wf, const float* __restrict__ seen,
                               unsigned short* __restrict__ wsb, float* __restrict__ s2) {
  int bid = blockIdx.x;
  if (bid < 264) {
    int idx = bid * 256 + (int)threadIdx.x;  // < 67584
    if (idx < 20480) {                       // W1: [128][160]
      int f = idx >> 9, r = idx & 511, L = r >> 3, j = r & 7;
      int t = f / 5, c = f - t * 5;
      int n = t * 16 + (L & 15), k = c * 32 + (L >> 4) * 8 + j;
      wsb[idx] = f2bf(W1[n * 160 + k]);
    } else if (idx < 36864) {                // W2: [128][128]
      int e = idx - 20480;
      int f = e >> 9, r = e & 511, L = r >> 3, j = r & 7;
      int t = f >> 2, c = f & 3;
      int n = t * 16 + (L & 15), k = c * 32 + (L >> 4) * 8 + j;
      wsb[idx] = f2bf(W2[n * 128 + k]);
    } else if (idx < 53248) {                // Wf: [128][128]
      int e = idx - 36864;
      int f = e >> 9, r = e & 511, L = r >> 3, j = r & 7;
      int t = f >> 2, c = f & 3;
      int n = t * 16 + (L & 15), k = c * 32 + (L >> 4) * 8 + j;
      wsb[idx] = f2bf(Wf[n * 128 + k]);
    } else {                                 // seen: [100->112][128]
      int e = idx - 53248;
      int f = e >> 9, r = e & 511, L = r >> 3, j = r & 7;
      int t = f >> 2, c = f & 3;
      int n = t * 16 + (L & 15), k = c * 32 + (L >> 4) * 8 + j;
      float v = (n < 100) ? seen[n * 128 + k] : 0.f;
      wsb[idx] = f2bf(v);
    }
  } else {                                   // s2: one wave per row
    int wv = (int)threadIdx.x >> 6, lane = (int)threadIdx.x & 63;
    int mm = (bid - 264) * 4 + wv;           // 0..111
    float s;
    if (mm < 100) {
      float v0 = seen[mm * 128 + lane], v1 = seen[mm * 128 + 64 + lane];
      s = v0 * v0 + v1 * v1;
#pragma unroll
      for (int msk = 1; msk < 64; msk <<= 1) s += __shfl_xor(s, msk, 64);
    } else {
      s = 1e30f;
    }
    if (lane == 0) s2[mm] = s;
  }
}

// pack two float4 (8 consecutive f32) into one bf16 A-fragment
__device__ __forceinline__ v8s cvt_frag(float4 lo, float4 hi) {
  union { v8s v; unsigned u[4]; } r;
  r.u[0] = f2bf2(lo.x, lo.y);
  r.u[1] = f2bf2(lo.z, lo.w);
  r.u[2] = f2bf2(hi.x, hi.y);
  r.u[3] = f2bf2(hi.z, hi.w);
  return r.v;
}

__device__ __forceinline__ v8s read_frag(const unsigned short* buf, int m, int q, int c) {
  return *(const v8s*)(buf + m * 136 + c * 32 + q * 8);
}

// async global->LDS, 16B per lane; dest is wave-uniform base + lane*16 (linear),
// source per-lane. wsb frag-linear layout == identity map both sides.
__device__ __forceinline__ void gload_lds16(const unsigned short* g, unsigned short* l) {
  __builtin_amdgcn_global_load_lds(
      (const __attribute__((address_space(1))) unsigned int*)g,
      (__attribute__((address_space(3))) unsigned int*)l, 16, 0, 0);
}
// stage nf frags (1 KB each) cooperatively: wave w takes frags w, w+4, ...
__device__ __forceinline__ void stage_chunk(const unsigned short* __restrict__ g,
                                            unsigned short* l, int nf, int w, int lane) {
  for (int i = w; i < nf; i += 4)
    gload_lds16(g + (size_t)i * 512 + lane * 8, l + i * 512);
}

// 20-chunk schedule: c0..7 = W1 (5 frags each, one tl), c8..11 = W2 (8 frags,
// 2 tl), c12..15 = Wf, c16..19 = seen (8,8,8,4).
__host__ __device__ constexpr int chunk_base(int c) {
  return c < 8  ? WS_W1 + c * 2560 :
         c < 12 ? WS_W2 + (c - 8) * 4096 :
         c < 16 ? WS_WF + (c - 12) * 4096 :
                  WS_SEEN + (c - 16) * 4096;
}
__host__ __device__ constexpr int chunk_nf(int c) { return c < 8 ? 5 : (c < 19 ? 8 : 4); }

// epilogue: acc + bias (opt relu) -> bf16 -> s_int
__device__ __forceinline__ void epi_store(unsigned short* bufT, v4f acc, float bv,
                                          int q, int tg, int m, bool relu) {
#pragma unroll
  for (int r = 0; r < 4; r += 2) {
    float x0 = acc[r] + bv, x1 = acc[r + 1] + bv;
    if (relu) { x0 = fmaxf(x0, 0.f); x1 = fmaxf(x1, 0.f); }
    unsigned p = f2bf2(x0, x1);
    bufT[(q * 4 + r) * 136 + tg * 16 + m] = (unsigned short)p;
    bufT[(q * 4 + r + 1) * 136 + tg * 16 + m] = (unsigned short)(p >> 16);
  }
}
// fused fa/fp epilogue: fa -> bf16 -> s_int, a2s += fa^2, pe += (fp-fa)^2
__device__ __forceinline__ void epi_fafp(unsigned short* bufT, v4f fav, v4f fpv, float bv,
                                         int q, int tg, int m, float* a2sT, float* peT) {
#pragma unroll
  for (int rp = 0; rp < 2; ++rp) {
    int r = rp * 2;
    unsigned p = f2bf2(fmaxf(fav[r] + bv, 0.f), fmaxf(fav[r + 1] + bv, 0.f));
    bufT[(q * 4 + r) * 136 + tg * 16 + m] = (unsigned short)p;
    bufT[(q * 4 + r + 1) * 136 + tg * 16 + m] = (unsigned short)(p >> 16);
    float flo = bf2f((unsigned short)p), fhi = bf2f((unsigned short)(p >> 16));
    a2sT[r] += flo * flo;
    a2sT[r + 1] += fhi * fhi;
    float d0 = fmaxf(fpv[r] + bv, 0.f) - flo;
    float d1 = fmaxf(fpv[r + 1] + bv, 0.f) - fhi;
    peT[r] += d0 * d0;
    peT[r + 1] += d1 * d1;
  }
}

// 2048 blocks x 256 threads; 4 waves/block; each wave owns 32 rows (2 row-tiles).
// Weights staged per-block into two 8 KB LDS chunks, double-buffered and rotated
// ahead-by-one so stage latency hides under the previous chunk's compute. All
// input bursts + biases issued in the prologue (one latency window). LDS =
// 16 + 34 + 1.5 = 51.5 KB -> 3 blocks/CU (12 waves).
__global__ __launch_bounds__(256, 3) void curiosity_main(
    const float* __restrict__ state, const float* __restrict__ action,
    const float* __restrict__ next_state,
    const float* __restrict__ b1, const float* __restrict__ b2,
    const float* __restrict__ bfv,
    const unsigned short* __restrict__ wsb, const float* __restrict__ s2g,
    float* __restrict__ out) {
  __shared__ __attribute__((aligned(16))) unsigned short s_wt[2][4096];  // 2 x 8 KB
  __shared__ __attribute__((aligned(16))) unsigned short s_int[4][2][2176];
  __shared__ float s_o[3][128];

  const int tid = (int)threadIdx.x;
  const int w = tid >> 6, lane = tid & 63;
  const int m = lane & 15, q = lane >> 4;
  const int rowblk = (int)blockIdx.x * 128 + w * 32;

  unsigned short* buf[2] = { &s_int[w][0][0], &s_int[w][1][0] };

  const float* st0 = state + (size_t)(rowblk + m) * 128 + q * 8;
  const float* st1 = st0 + 16 * 128;
  const float* ac0 = action + (size_t)(rowblk + m) * 32 + q * 8;
  const float* ac1 = ac0 + 16 * 32;
  const float* np0 = next_state + (size_t)(rowblk + m) * 128 + q * 8;
  const float* np1 = np0 + 16 * 128;

  // ---- prologue: all input bursts + biases + first two stage chunks in one
  //      latency window, drained by a single barrier.
  float4 sv[2][4][2], av[2][2], nv[2][4][2];
#pragma unroll
  for (int c = 0; c < 4; ++c) {
    sv[0][c][0] = *(const float4*)(st0 + c * 32);
    sv[0][c][1] = *(const float4*)(st0 + c * 32 + 4);
    sv[1][c][0] = *(const float4*)(st1 + c * 32);
    sv[1][c][1] = *(const float4*)(st1 + c * 32 + 4);
  }
  av[0][0] = *(const float4*)(ac0); av[0][1] = *(const float4*)(ac0 + 4);
  av[1][0] = *(const float4*)(ac1); av[1][1] = *(const float4*)(ac1 + 4);
  stage_chunk(wsb + chunk_base(0), s_wt[0], chunk_nf(0), w, lane);
  stage_chunk(wsb + chunk_base(1), s_wt[1], chunk_nf(1), w, lane);
#pragma unroll
  for (int c = 0; c < 4; ++c) {
    nv[0][c][0] = *(const float4*)(np0 + c * 32);
    nv[0][c][1] = *(const float4*)(np0 + c * 32 + 4);
    nv[1][c][0] = *(const float4*)(np1 + c * 32);
    nv[1][c][1] = *(const float4*)(np1 + c * 32 + 4);
  }
  float bv1[8], bv2[8], bvf[8];
#pragma unroll
  for (int tg = 0; tg < 8; ++tg) bv1[tg] = b1[tg * 16 + m];
#pragma unroll
  for (int tg = 0; tg < 8; ++tg) bv2[tg] = b2[tg * 16 + m];
#pragma unroll
  for (int tg = 0; tg < 8; ++tg) bvf[tg] = bfv[tg * 16 + m];

  // convert state/action while next_state still in flight (in-order vmcnt)
  v8s a1[2][5];
#pragma unroll
  for (int c = 0; c < 4; ++c) {
    a1[0][c] = cvt_frag(sv[0][c][0], sv[0][c][1]);
    a1[1][c] = cvt_frag(sv[1][c][0], sv[1][c][1]);
  }
  a1[0][4] = cvt_frag(av[0][0], av[0][1]);
  a1[1][4] = cvt_frag(av[1][0], av[1][1]);
  __syncthreads();                      // chunk0/1 staged, inputs drained
  v8s a3[2][4];
#pragma unroll
  for (int c = 0; c < 4; ++c) {
    a3[0][c] = cvt_frag(nv[0][c][0], nv[0][c][1]);
    a3[1][c] = cvt_frag(nv[1][c][0], nv[1][c][1]);
  }

  // ---- GEMM1: h = relu(x @ W1^T + b1); phases 0..7, one tl each
#pragma unroll
  for (int p = 0; p < 8; ++p) {
    if (p >= 1)
      stage_chunk(wsb + chunk_base(p + 1), s_wt[(p + 1) & 1], chunk_nf(p + 1), w, lane);
    const unsigned short* sb = s_wt[p & 1];
    v8s bfr[5];
#pragma unroll
    for (int c = 0; c < 5; ++c) bfr[c] = *(const v8s*)(sb + c * 512 + lane * 8);
    v4f acc[2] = {};
#pragma unroll
    for (int c = 0; c < 5; ++c) {
      acc[0] = MFMA(a1[0][c], bfr[c], acc[0], 0, 0, 0);
      acc[1] = MFMA(a1[1][c], bfr[c], acc[1], 0, 0, 0);
    }
    epi_store(buf[0], acc[0], bv1[p], q, p, m, true);
    epi_store(buf[1], acc[1], bv1[p], q, p, m, true);
    __syncthreads();
  }

  // ---- GEMM2: pn = h @ W2^T + b2; phases 8..11, two tl each
  v8s af[2][4];
#pragma unroll
  for (int c = 0; c < 4; ++c) {
    af[0][c] = read_frag(buf[0], m, q, c);
    af[1][c] = read_frag(buf[1], m, q, c);
  }
#pragma unroll
  for (int p = 8; p < 12; ++p) {
    stage_chunk(wsb + chunk_base(p + 1), s_wt[(p + 1) & 1], chunk_nf(p + 1), w, lane);
    const unsigned short* sb = s_wt[p & 1];
#pragma unroll
    for (int tl2 = 0; tl2 < 2; ++tl2) {
      v8s bfr[4];
#pragma unroll
      for (int c = 0; c < 4; ++c) bfr[c] = *(const v8s*)(sb + (tl2 * 4 + c) * 512 + lane * 8);
      v4f acc[2] = {};
#pragma unroll
      for (int c = 0; c < 4; ++c) {
        acc[0] = MFMA(af[0][c], bfr[c], acc[0], 0, 0, 0);
        acc[1] = MFMA(af[1][c], bfr[c], acc[1], 0, 0, 0);
      }
      int tg = (p - 8) * 2 + tl2;
      epi_store(buf[0], acc[0], bv2[tg], q, tg, m, false);
      epi_store(buf[1], acc[1], bv2[tg], q, tg, m, false);
    }
    __syncthreads();
  }

  // ---- fused GEMM3+GEMM4; phases 12..15, two tl each
  v8s a4[2][4];
#pragma unroll
  for (int c = 0; c < 4; ++c) {
    a4[0][c] = read_frag(buf[0], m, q, c);
    a4[1][c] = read_frag(buf[1], m, q, c);
  }
  float pe[2][4] = {};
  float a2s[2][4] = {};
  float s2v[7];
#pragma unroll
  for (int p = 12; p < 16; ++p) {
    stage_chunk(wsb + chunk_base(p + 1), s_wt[(p + 1) & 1], chunk_nf(p + 1), w, lane);
    if (p == 15) {
#pragma unroll
      for (int tl = 0; tl < 7; ++tl) s2v[tl] = s2g[tl * 16 + m];
    }
    const unsigned short* sb = s_wt[p & 1];
#pragma unroll
    for (int tl2 = 0; tl2 < 2; ++tl2) {
      v8s bfr[4];
#pragma unroll
      for (int c = 0; c < 4; ++c) bfr[c] = *(const v8s*)(sb + (tl2 * 4 + c) * 512 + lane * 8);
      v4f fa0 = {}, fa1 = {}, fp0 = {}, fp1 = {};
#pragma unroll
      for (int c = 0; c < 4; ++c) {
        fa0 = MFMA(a3[0][c], bfr[c], fa0, 0, 0, 0);
        fa1 = MFMA(a3[1][c], bfr[c], fa1, 0, 0, 0);
        fp0 = MFMA(a4[0][c], bfr[c], fp0, 0, 0, 0);
        fp1 = MFMA(a4[1][c], bfr[c], fp1, 0, 0, 0);
      }
      int tg = (p - 12) * 2 + tl2;
      epi_fafp(buf[0], fa0, fp0, bvf[tg], q, tg, m, a2s[0], pe[0]);
      epi_fafp(buf[1], fa1, fp1, bvf[tg], q, tg, m, a2s[1], pe[1]);
    }
    __syncthreads();
  }

  // ---- GEMM5: g = fa @ seen^T; phases 16..19 (8,8,8,4 frags)
  float dmin[2][4] = {{3.4e38f, 3.4e38f, 3.4e38f, 3.4e38f},
                      {3.4e38f, 3.4e38f, 3.4e38f, 3.4e38f}};
  v8s a5[2][4];
#pragma unroll
  for (int p = 16; p < 20; ++p) {
    if (p < 19)
      stage_chunk(wsb + chunk_base(p + 1), s_wt[(p + 1) & 1], chunk_nf(p + 1), w, lane);
    if (p == 16) {
      // slot the pe/a2s quad-reduce + fa A-frag reads under chunk17's stage
#pragma unroll
      for (int tt = 0; tt < 2; ++tt)
#pragma unroll
        for (int r = 0; r < 4; ++r)
#pragma unroll
          for (int msk = 1; msk < 16; msk <<= 1) {
            pe[tt][r] += __shfl_xor(pe[tt][r], msk, 16);
            a2s[tt][r] += __shfl_xor(a2s[tt][r], msk, 16);
          }
#pragma unroll
      for (int c = 0; c < 4; ++c) {
        a5[0][c] = read_frag(buf[0], m, q, c);
        a5[1][c] = read_frag(buf[1], m, q, c);
      }
    }
    const unsigned short* sb = s_wt[p & 1];
    const int ntl = (p == 19) ? 1 : 2;
#pragma unroll
    for (int tl2 = 0; tl2 < 2; ++tl2) {
      if (tl2 >= ntl) break;
      v8s bfr[4];
#pragma unroll
      for (int c = 0; c < 4; ++c) bfr[c] = *(const v8s*)(sb + (tl2 * 4 + c) * 512 + lane * 8);
      v4f g0 = {}, g1 = {};
#pragma unroll
      for (int c = 0; c < 4; ++c) {
        g0 = MFMA(a5[0][c], bfr[c], g0, 0, 0, 0);
        g1 = MFMA(a5[1][c], bfr[c], g1, 0, 0, 0);
      }
      float s2x = s2v[(p - 16) * 2 + tl2];
#pragma unroll
      for (int r = 0; r < 4; ++r) {
        dmin[0][r] = fminf(dmin[0][r], a2s[0][r] + s2x - 2.f * g0[r]);
        dmin[1][r] = fminf(dmin[1][r], a2s[1][r] + s2x - 2.f * g1[r]);
      }
    }
    if (p < 19) __syncthreads();
  }

#pragma unroll
  for (int tt = 0; tt < 2; ++tt)
#pragma unroll
    for (int r = 0; r < 4; ++r)
#pragma unroll
      for (int msk = 1; msk < 16; msk <<= 1)
        dmin[tt][r] = fminf(dmin[tt][r], __shfl_xor(dmin[tt][r], msk, 16));

  if (m == 0) {
#pragma unroll
    for (int tt = 0; tt < 2; ++tt)
#pragma unroll
      for (int r = 0; r < 4; ++r) {
        int rl = w * 32 + tt * 16 + q * 4 + r;
        float p = pe[tt][r] * (1.f / 128.f);
        float nov = fminf(1.f, sqrtf(fmaxf(dmin[tt][r], 0.f)) * 0.1f);
        s_o[0][rl] = p;
        s_o[1][rl] = nov;
        s_o[2][rl] = 0.5f * (p + nov);
      }
  }
  __syncthreads();
  const size_t base = (size_t)blockIdx.x * 128;
  for (int idx = tid; idx < 384; idx += 256) {
    int j = idx >> 7, r = idx & 127;
    out[(size_t)j * B_TOT + base + r] = s_o[j][r];
  }
}

extern "C" void kernel_launch(void* const* d_in, const int* in_sizes, int n_in,
                              void* d_out, int out_size, void* d_ws, size_t ws_size,
                              hipStream_t stream) {
  const float* state      = (const float*)d_in[0];
  const float* action     = (const float*)d_in[1];
  const float* next_state = (const float*)d_in[2];
  const float* seen       = (const float*)d_in[3];
  const float* W1         = (const float*)d_in[4];
  const float* b1         = (const float*)d_in[5];
  const float* W2         = (const float*)d_in[6];
  const float* b2         = (const float*)d_in[7];
  const float* Wf         = (const float*)d_in[8];
  const float* bf_        = (const float*)d_in[9];

  unsigned short* wsb = (unsigned short*)d_ws;
  float* s2 = (float*)((char*)d_ws + WS_S2_BYTES);

  curiosity_prep<<<292, 256, 0, stream>>>(W1, W2, Wf, seen, wsb, s2);
  curiosity_main<<<2048, 256, 0, stream>>>(state, action, next_state, b1, b2, bf_,
                                           wsb, s2, (float*)d_out);
}

// Round 4
// 343.337 us; speedup vs baseline: 1.0927x; 1.0927x over previous
//
#include <hip/hip_runtime.h>
#include <hip/hip_bf16.h>
#include <math.h>

#define B_TOT 262144

typedef __attribute__((ext_vector_type(8))) short v8s;
typedef __attribute__((ext_vector_type(4))) float v4f;

// ws layout (bf16 element offsets):
//  W1 frag-order   [0, 20480)        (8 n-tiles x 5 k-chunks x 512)
//  W2 frag-order   [20480, 36864)    (8 x 4 x 512)
//  Wf frag-order   [36864, 53248)    (8 x 4 x 512)
//  seen frag-order [53248, 67584)    (7 x 4 x 512, rows >=100 zero-padded)
//  s2 (fp32)       byte offset 135168, 112 floats (1e30 for pad rows)
#define WS_W1 0
#define WS_W2 20480
#define WS_WF 36864
#define WS_SEEN 53248
#define WS_S2_BYTES 135168

#define MFMA __builtin_amdgcn_mfma_f32_16x16x32_bf16

__device__ __forceinline__ unsigned short f2bf(float f) {
  union { float f; unsigned u; } cv; cv.f = f;
  unsigned u = cv.u;
  return (unsigned short)((u + 0x7FFFu + ((u >> 16) & 1u)) >> 16);  // RNE
}
__device__ __forceinline__ float bf2f(unsigned short h) {
  union { unsigned u; float f; } cv; cv.u = ((unsigned)h) << 16;
  return cv.f;
}
// packed RNE f32x2 -> bf16x2 (v_cvt_pk_bf16_f32 on gfx950); low 16 = x
__device__ __forceinline__ unsigned f2bf2(float x, float y) {
  float2 f; f.x = x; f.y = y;
  __hip_bfloat162 h = __float22bfloat162_rn(f);
  union { __hip_bfloat162 h; unsigned u; } cv; cv.h = h;
  return cv.u;
}

// Repack weights to bf16 in MFMA B-fragment-linear order.
// B-frag for (tile t, k-chunk c): lane L holds B[n = t*16 + (L&15)][k = c*32 + (L>>4)*8 + j]
__global__ void curiosity_prep(const float* __restrict__ W1, const float* __restrict__ W2,
                               const float* __restrict__ Wf, const float* __restrict__ seen,
                               unsigned short* __restrict__ wsb, float* __restrict__ s2) {
  int bid = blockIdx.x;
  if (bid < 264) {
    int idx = bid * 256 + (int)threadIdx.x;  // < 67584
    if (idx < 20480) {                       // W1: [128][160]
      int f = idx >> 9, r = idx & 511, L = r >> 3, j = r & 7;
      int t = f / 5, c = f - t * 5;
      int n = t * 16 + (L & 15), k = c * 32 + (L >> 4) * 8 + j;
      wsb[idx] = f2bf(W1[n * 160 + k]);
    } else if (idx < 36864) {                // W2: [128][128]
      int e = idx - 20480;
      int f = e >> 9, r = e & 511, L = r >> 3, j = r & 7;
      int t = f >> 2, c = f & 3;
      int n = t * 16 + (L & 15), k = c * 32 + (L >> 4) * 8 + j;
      wsb[idx] = f2bf(W2[n * 128 + k]);
    } else if (idx < 53248) {                // Wf: [128][128]
      int e = idx - 36864;
      int f = e >> 9, r = e & 511, L = r >> 3, j = r & 7;
      int t = f >> 2, c = f & 3;
      int n = t * 16 + (L & 15), k = c * 32 + (L >> 4) * 8 + j;
      wsb[idx] = f2bf(Wf[n * 128 + k]);
    } else {                                 // seen: [100->112][128]
      int e = idx - 53248;
      int f = e >> 9, r = e & 511, L = r >> 3, j = r & 7;
      int t = f >> 2, c = f & 3;
      int n = t * 16 + (L & 15), k = c * 32 + (L >> 4) * 8 + j;
      float v = (n < 100) ? seen[n * 128 + k] : 0.f;
      wsb[idx] = f2bf(v);
    }
  } else {                                   // s2: one wave per row
    int wv = (int)threadIdx.x >> 6, lane = (int)threadIdx.x & 63;
    int mm = (bid - 264) * 4 + wv;           // 0..111
    float s;
    if (mm < 100) {
      float v0 = seen[mm * 128 + lane], v1 = seen[mm * 128 + 64 + lane];
      s = v0 * v0 + v1 * v1;
#pragma unroll
      for (int msk = 1; msk < 64; msk <<= 1) s += __shfl_xor(s, msk, 64);
    } else {
      s = 1e30f;
    }
    if (lane == 0) s2[mm] = s;
  }
}

// pack two float4 (8 consecutive f32) into one bf16 A-fragment
__device__ __forceinline__ v8s cvt_frag(float4 lo, float4 hi) {
  union { v8s v; unsigned u[4]; } r;
  r.u[0] = f2bf2(lo.x, lo.y);
  r.u[1] = f2bf2(lo.z, lo.w);
  r.u[2] = f2bf2(hi.x, hi.y);
  r.u[3] = f2bf2(hi.z, hi.w);
  return r.v;
}

__device__ __forceinline__ v8s read_frag(const unsigned short* buf, int m, int q, int c) {
  return *(const v8s*)(buf + m * 136 + c * 32 + q * 8);
}

// async global->LDS, 16B per lane; dest is wave-uniform base + lane*16 (linear),
// source per-lane. wsb frag-linear layout == identity map both sides.
__device__ __forceinline__ void gload_lds16(const unsigned short* g, unsigned short* l) {
  __builtin_amdgcn_global_load_lds(
      (const __attribute__((address_space(1))) unsigned int*)g,
      (__attribute__((address_space(3))) unsigned int*)l, 16, 0, 0);
}
// stage nf frags (1 KB each) cooperatively: wave w takes frags w, w+4, ...
__device__ __forceinline__ void stage_chunk(const unsigned short* __restrict__ g,
                                            unsigned short* l, int nf, int w, int lane) {
  for (int i = w; i < nf; i += 4)
    gload_lds16(g + (size_t)i * 512 + lane * 8, l + i * 512);
}

// 20-chunk schedule: c0..7 = W1 (5 frags each, one tl), c8..11 = W2 (8 frags,
// 2 tl), c12..15 = Wf, c16..19 = seen (8,8,8,4).
__host__ __device__ constexpr int chunk_base(int c) {
  return c < 8  ? WS_W1 + c * 2560 :
         c < 12 ? WS_W2 + (c - 8) * 4096 :
         c < 16 ? WS_WF + (c - 12) * 4096 :
                  WS_SEEN + (c - 16) * 4096;
}
__host__ __device__ constexpr int chunk_nf(int c) { return c < 8 ? 5 : (c < 19 ? 8 : 4); }

// epilogue: acc + bias (opt relu) -> bf16 -> s_int
__device__ __forceinline__ void epi_store(unsigned short* bufT, v4f acc, float bv,
                                          int q, int tg, int m, bool relu) {
#pragma unroll
  for (int r = 0; r < 4; r += 2) {
    float x0 = acc[r] + bv, x1 = acc[r + 1] + bv;
    if (relu) { x0 = fmaxf(x0, 0.f); x1 = fmaxf(x1, 0.f); }
    unsigned p = f2bf2(x0, x1);
    bufT[(q * 4 + r) * 136 + tg * 16 + m] = (unsigned short)p;
    bufT[(q * 4 + r + 1) * 136 + tg * 16 + m] = (unsigned short)(p >> 16);
  }
}
// fused fa/fp epilogue: fa -> bf16 -> s_int, a2s += fa^2, pe += (fp-fa)^2
__device__ __forceinline__ void epi_fafp(unsigned short* bufT, v4f fav, v4f fpv, float bv,
                                         int q, int tg, int m, float* a2sT, float* peT) {
#pragma unroll
  for (int rp = 0; rp < 2; ++rp) {
    int r = rp * 2;
    unsigned p = f2bf2(fmaxf(fav[r] + bv, 0.f), fmaxf(fav[r + 1] + bv, 0.f));
    bufT[(q * 4 + r) * 136 + tg * 16 + m] = (unsigned short)p;
    bufT[(q * 4 + r + 1) * 136 + tg * 16 + m] = (unsigned short)(p >> 16);
    float flo = bf2f((unsigned short)p), fhi = bf2f((unsigned short)(p >> 16));
    a2sT[r] += flo * flo;
    a2sT[r + 1] += fhi * fhi;
    float d0 = fmaxf(fpv[r] + bv, 0.f) - flo;
    float d1 = fmaxf(fpv[r + 1] + bv, 0.f) - fhi;
    peT[r] += d0 * d0;
    peT[r + 1] += d1 * d1;
  }
}

// 2048 blocks x 256 threads; 4 waves/block; each wave owns 32 rows (2 row-tiles).
// Weights staged per-block into two 8 KB ping-pong LDS chunks, rotated ahead-by-
// one so stage latency hides under the previous chunk's compute. LDS = 16 + 34 +
// 1.5 = 52.7 KB -> 3 blocks/CU by LDS. launch_bounds(256,2): R2-proven codegen
// (no spills); 3-block residency comes from actual VGPR use (<=168), not the
// hint. Input live ranges staggered exactly as R2: state+action in prologue,
// next_state issued at GEMM2 entry / converted at GEMM3 entry, biases at region
// entry.
__global__ __launch_bounds__(256, 2) void curiosity_main(
    const float* __restrict__ state, const float* __restrict__ action,
    const float* __restrict__ next_state,
    const float* __restrict__ b1, const float* __restrict__ b2,
    const float* __restrict__ bfv,
    const unsigned short* __restrict__ wsb, const float* __restrict__ s2g,
    float* __restrict__ out) {
  __shared__ __attribute__((aligned(16))) unsigned short s_wt[2][4096];  // 2 x 8 KB
  __shared__ __attribute__((aligned(16))) unsigned short s_int[4][2][2176];
  __shared__ float s_o[3][128];

  const int tid = (int)threadIdx.x;
  const int w = tid >> 6, lane = tid & 63;
  const int m = lane & 15, q = lane >> 4;
  const int rowblk = (int)blockIdx.x * 128 + w * 32;

  unsigned short* buf[2] = { &s_int[w][0][0], &s_int[w][1][0] };

  const float* st0 = state + (size_t)(rowblk + m) * 128 + q * 8;
  const float* st1 = st0 + 16 * 128;
  const float* ac0 = action + (size_t)(rowblk + m) * 32 + q * 8;
  const float* ac1 = ac0 + 16 * 32;
  const float* np0 = next_state + (size_t)(rowblk + m) * 128 + q * 8;
  const float* np1 = np0 + 16 * 128;

  // ---- prologue: state+action burst (20 dwordx4) + stage c0/c1 + b1, one
  //      latency window drained by a single barrier. next_state NOT loaded here.
  float4 sv[2][4][2], av[2][2];
#pragma unroll
  for (int c = 0; c < 4; ++c) {
    sv[0][c][0] = *(const float4*)(st0 + c * 32);
    sv[0][c][1] = *(const float4*)(st0 + c * 32 + 4);
    sv[1][c][0] = *(const float4*)(st1 + c * 32);
    sv[1][c][1] = *(const float4*)(st1 + c * 32 + 4);
  }
  av[0][0] = *(const float4*)(ac0); av[0][1] = *(const float4*)(ac0 + 4);
  av[1][0] = *(const float4*)(ac1); av[1][1] = *(const float4*)(ac1 + 4);
  stage_chunk(wsb + chunk_base(0), s_wt[0], chunk_nf(0), w, lane);
  stage_chunk(wsb + chunk_base(1), s_wt[1], chunk_nf(1), w, lane);
  float bv1[8];
#pragma unroll
  for (int tg = 0; tg < 8; ++tg) bv1[tg] = b1[tg * 16 + m];

  // convert state/action while stages drain
  v8s a1[2][5];
#pragma unroll
  for (int c = 0; c < 4; ++c) {
    a1[0][c] = cvt_frag(sv[0][c][0], sv[0][c][1]);
    a1[1][c] = cvt_frag(sv[1][c][0], sv[1][c][1]);
  }
  a1[0][4] = cvt_frag(av[0][0], av[0][1]);
  a1[1][4] = cvt_frag(av[1][0], av[1][1]);
  __syncthreads();                      // c0/c1 staged

  // ---- GEMM1: h = relu(x @ W1^T + b1); phases 0..7, one tl each
#pragma unroll
  for (int p = 0; p < 8; ++p) {
    if (p >= 1)
      stage_chunk(wsb + chunk_base(p + 1), s_wt[(p + 1) & 1], chunk_nf(p + 1), w, lane);
    const unsigned short* sb = s_wt[p & 1];
    v8s bfr[5];
#pragma unroll
    for (int c = 0; c < 5; ++c) bfr[c] = *(const v8s*)(sb + c * 512 + lane * 8);
    v4f acc[2] = {};
#pragma unroll
    for (int c = 0; c < 5; ++c) {
      acc[0] = MFMA(a1[0][c], bfr[c], acc[0], 0, 0, 0);
      acc[1] = MFMA(a1[1][c], bfr[c], acc[1], 0, 0, 0);
    }
    epi_store(buf[0], acc[0], bv1[p], q, p, m, true);
    epi_store(buf[1], acc[1], bv1[p], q, p, m, true);
    __syncthreads();
  }

  // ---- GEMM2: pn = h @ W2^T + b2; phases 8..11, two tl each.
  //      next_state burst issued HERE (R2 placement): drains at the phase-11
  //      barrier, hidden under GEMM2 compute; converted at GEMM3 entry.
  v8s af[2][4];
#pragma unroll
  for (int c = 0; c < 4; ++c) {
    af[0][c] = read_frag(buf[0], m, q, c);
    af[1][c] = read_frag(buf[1], m, q, c);
  }
  float4 nv[2][4][2];
#pragma unroll
  for (int c = 0; c < 4; ++c) {
    nv[0][c][0] = *(const float4*)(np0 + c * 32);
    nv[0][c][1] = *(const float4*)(np0 + c * 32 + 4);
    nv[1][c][0] = *(const float4*)(np1 + c * 32);
    nv[1][c][1] = *(const float4*)(np1 + c * 32 + 4);
  }
  float bv2[8];
#pragma unroll
  for (int tg = 0; tg < 8; ++tg) bv2[tg] = b2[tg * 16 + m];
#pragma unroll
  for (int p = 8; p < 12; ++p) {
    stage_chunk(wsb + chunk_base(p + 1), s_wt[(p + 1) & 1], chunk_nf(p + 1), w, lane);
    const unsigned short* sb = s_wt[p & 1];
#pragma unroll
    for (int tl2 = 0; tl2 < 2; ++tl2) {
      v8s bfr[4];
#pragma unroll
      for (int c = 0; c < 4; ++c) bfr[c] = *(const v8s*)(sb + (tl2 * 4 + c) * 512 + lane * 8);
      v4f acc[2] = {};
#pragma unroll
      for (int c = 0; c < 4; ++c) {
        acc[0] = MFMA(af[0][c], bfr[c], acc[0], 0, 0, 0);
        acc[1] = MFMA(af[1][c], bfr[c], acc[1], 0, 0, 0);
      }
      int tg = (p - 8) * 2 + tl2;
      epi_store(buf[0], acc[0], bv2[tg], q, tg, m, false);
      epi_store(buf[1], acc[1], bv2[tg], q, tg, m, false);
    }
    __syncthreads();
  }

  // ---- fused GEMM3+GEMM4; phases 12..15, two tl each
  v8s a4[2][4];
#pragma unroll
  for (int c = 0; c < 4; ++c) {
    a4[0][c] = read_frag(buf[0], m, q, c);
    a4[1][c] = read_frag(buf[1], m, q, c);
  }
  v8s a3[2][4];
#pragma unroll
  for (int c = 0; c < 4; ++c) {
    a3[0][c] = cvt_frag(nv[0][c][0], nv[0][c][1]);
    a3[1][c] = cvt_frag(nv[1][c][0], nv[1][c][1]);
  }
  float bvf[8];
#pragma unroll
  for (int tg = 0; tg < 8; ++tg) bvf[tg] = bfv[tg * 16 + m];
  float pe[2][4] = {};
  float a2s[2][4] = {};
#pragma unroll
  for (int p = 12; p < 16; ++p) {
    stage_chunk(wsb + chunk_base(p + 1), s_wt[(p + 1) & 1], chunk_nf(p + 1), w, lane);
    const unsigned short* sb = s_wt[p & 1];
#pragma unroll
    for (int tl2 = 0; tl2 < 2; ++tl2) {
      v8s bfr[4];
#pragma unroll
      for (int c = 0; c < 4; ++c) bfr[c] = *(const v8s*)(sb + (tl2 * 4 + c) * 512 + lane * 8);
      v4f fa0 = {}, fa1 = {}, fp0 = {}, fp1 = {};
#pragma unroll
      for (int c = 0; c < 4; ++c) {
        fa0 = MFMA(a3[0][c], bfr[c], fa0, 0, 0, 0);
        fa1 = MFMA(a3[1][c], bfr[c], fa1, 0, 0, 0);
        fp0 = MFMA(a4[0][c], bfr[c], fp0, 0, 0, 0);
        fp1 = MFMA(a4[1][c], bfr[c], fp1, 0, 0, 0);
      }
      int tg = (p - 12) * 2 + tl2;
      epi_fafp(buf[0], fa0, fp0, bvf[tg], q, tg, m, a2s[0], pe[0]);
      epi_fafp(buf[1], fa1, fp1, bvf[tg], q, tg, m, a2s[1], pe[1]);
    }
    __syncthreads();
  }

  // ---- GEMM5: g = fa @ seen^T; phases 16..19 (8,8,8,4 frags)
  float s2v[7];
#pragma unroll
  for (int tl = 0; tl < 7; ++tl) s2v[tl] = s2g[tl * 16 + m];
  float dmin[2][4] = {{3.4e38f, 3.4e38f, 3.4e38f, 3.4e38f},
                      {3.4e38f, 3.4e38f, 3.4e38f, 3.4e38f}};
  v8s a5[2][4];
#pragma unroll
  for (int p = 16; p < 20; ++p) {
    if (p < 19)
      stage_chunk(wsb + chunk_base(p + 1), s_wt[(p + 1) & 1], chunk_nf(p + 1), w, lane);
    if (p == 16) {
      // slot the pe/a2s quad-reduce + fa A-frag reads under chunk17's stage
#pragma unroll
      for (int tt = 0; tt < 2; ++tt)
#pragma unroll
        for (int r = 0; r < 4; ++r)
#pragma unroll
          for (int msk = 1; msk < 16; msk <<= 1) {
            pe[tt][r] += __shfl_xor(pe[tt][r], msk, 16);
            a2s[tt][r] += __shfl_xor(a2s[tt][r], msk, 16);
          }
#pragma unroll
      for (int c = 0; c < 4; ++c) {
        a5[0][c] = read_frag(buf[0], m, q, c);
        a5[1][c] = read_frag(buf[1], m, q, c);
      }
    }
    const unsigned short* sb = s_wt[p & 1];
    const int ntl = (p == 19) ? 1 : 2;
#pragma unroll
    for (int tl2 = 0; tl2 < 2; ++tl2) {
      if (tl2 >= ntl) break;
      v8s bfr[4];
#pragma unroll
      for (int c = 0; c < 4; ++c) bfr[c] = *(const v8s*)(sb + (tl2 * 4 + c) * 512 + lane * 8);
      v4f g0 = {}, g1 = {};
#pragma unroll
      for (int c = 0; c < 4; ++c) {
        g0 = MFMA(a5[0][c], bfr[c], g0, 0, 0, 0);
        g1 = MFMA(a5[1][c], bfr[c], g1, 0, 0, 0);
      }
      float s2x = s2v[(p - 16) * 2 + tl2];
#pragma unroll
      for (int r = 0; r < 4; ++r) {
        dmin[0][r] = fminf(dmin[0][r], a2s[0][r] + s2x - 2.f * g0[r]);
        dmin[1][r] = fminf(dmin[1][r], a2s[1][r] + s2x - 2.f * g1[r]);
      }
    }
    if (p < 19) __syncthreads();
  }

#pragma unroll
  for (int tt = 0; tt < 2; ++tt)
#pragma unroll
    for (int r = 0; r < 4; ++r)
#pragma unroll
      for (int msk = 1; msk < 16; msk <<= 1)
        dmin[tt][r] = fminf(dmin[tt][r], __shfl_xor(dmin[tt][r], msk, 16));

  if (m == 0) {
#pragma unroll
    for (int tt = 0; tt < 2; ++tt)
#pragma unroll
      for (int r = 0; r < 4; ++r) {
        int rl = w * 32 + tt * 16 + q * 4 + r;
        float p = pe[tt][r] * (1.f / 128.f);
        float nov = fminf(1.f, sqrtf(fmaxf(dmin[tt][r], 0.f)) * 0.1f);
        s_o[0][rl] = p;
        s_o[1][rl] = nov;
        s_o[2][rl] = 0.5f * (p + nov);
      }
  }
  __syncthreads();
  const size_t base = (size_t)blockIdx.x * 128;
  for (int idx = tid; idx < 384; idx += 256) {
    int j = idx >> 7, r = idx & 127;
    out[(size_t)j * B_TOT + base + r] = s_o[j][r];
  }
}

extern "C" void kernel_launch(void* const* d_in, const int* in_sizes, int n_in,
                              void* d_out, int out_size, void* d_ws, size_t ws_size,
                              hipStream_t stream) {
  const float* state      = (const float*)d_in[0];
  const float* action     = (const float*)d_in[1];
  const float* next_state = (const float*)d_in[2];
  const float* seen       = (const float*)d_in[3];
  const float* W1         = (const float*)d_in[4];
  const float* b1         = (const float*)d_in[5];
  const float* W2         = (const float*)d_in[6];
  const float* b2         = (const float*)d_in[7];
  const float* Wf         = (const float*)d_in[8];
  const float* bf_        = (const float*)d_in[9];

  unsigned short* wsb = (unsigned short*)d_ws;
  float* s2 = (float*)((char*)d_ws + WS_S2_BYTES);

  curiosity_prep<<<292, 256, 0, stream>>>(W1, W2, Wf, seen, wsb, s2);
  curiosity_main<<<2048, 256, 0, stream>>>(state, action, next_state, b1, b2, bf_,
                                           wsb, s2, (float*)d_out);
}